// Round 8
// baseline (405.852 us; speedup 1.0000x reference)
//
#include <hip/hip_runtime.h>
#include <stdint.h>

// Output layout (float32 elements within d_out):
//   q_out : [8][1024][64][64]  at offset 0          (33,554,432)
//   code  : [8][4][64][64]     at offset 33,554,432 (131,072)  -- stored as float
//   logit : [8][1024][64][64]  at offset 33,685,504 (33,554,432)
#define CODE_OFF  33554432u
#define LOGIT_OFF 33685504u

typedef __attribute__((address_space(1))) const void g_void;
typedef __attribute__((address_space(3))) void l_void;

__device__ __forceinline__ uint32_t rotl32(uint32_t x, int r) {
  return (x << r) | (x >> (32 - r));
}

// Partitionable threefry (JAX >= 0.4.36 default): counter words (0, flat_idx),
// key (0,42), 20 rounds, draw = o0 ^ o1. Verified bit-exact in round 2.
__device__ __forceinline__ uint32_t tf32_part(uint32_t i) {
  const uint32_t ks1 = 42u;
  const uint32_t ks2 = 0x1BD11BDAu ^ 42u;  // ks0 = 0
  uint32_t x0 = 0u;
  uint32_t x1 = i + ks1;
#define R4(a,b,c,d) \
  x0 += x1; x1 = rotl32(x1,(a)); x1 ^= x0; \
  x0 += x1; x1 = rotl32(x1,(b)); x1 ^= x0; \
  x0 += x1; x1 = rotl32(x1,(c)); x1 ^= x0; \
  x0 += x1; x1 = rotl32(x1,(d)); x1 ^= x0;
  R4(13,15,26,6)   x0 += ks1; x1 += ks2 + 1u;
  R4(17,29,16,24)  x0 += ks2; x1 += 2u;
  R4(13,15,26,6)               x1 += ks1 + 3u;
  R4(17,29,16,24)  x0 += ks1; x1 += ks2 + 4u;
  R4(13,15,26,6)   x0 += ks2; x1 += 5u;
#undef R4
  return x0 ^ x1;
}

__device__ __forceinline__ float bits_to_gumbel(uint32_t bits) {
  uint32_t fb = (bits >> 9) | 0x3f800000u;
  float f = __uint_as_float(fb) - 1.0f;
  float u = (f > 0.0f) ? f : 1.17549435e-38f;
  return -logf(-logf(u));
}

// Grid 4096, block 256 (4 waves). tx = tid&7: half = tx>>2 (n vs n+4),
// px = tx&3 -> 4 consecutive hw positions hw0 + 4*px + p (16-pos tile).
// ty = tid>>3 in [0,32): 8 k's per thread, k = (jd>>2)*128 + ty*4 + (jd&3).
// K-loop: 16 chunks of 4 channels; w double-buffered in LDS (1 barrier/chunk);
// 2 threefry+gumbel draws per chunk. Identical per-thread work and c-ascending
// FMA chain order to the 382.7-best kernel; the only change is the LDS
// footprint: 24 KB -> 16 KB (w dbuf 16->8 KB), lifting the blocks/CU cap from
// 5-6 to 8-10 (VGPR 44 allows 8). Scalar FMAs (pk_fma is half-rate on the
// SIMD-32 datapath -- R7 measured regression).
__global__ __launch_bounds__(256, 4)
void mcq_kernel(const float* __restrict__ x, const float* __restrict__ w,
                float* __restrict__ out) {
  __shared__ __align__(16) float x_lds[2048];  // [c(64)][half*16 + pos(16)]
  __shared__ __align__(16) float w_lds[2048];  // 2 x [cc(4)][k(256)] buffers

  const int tid = threadIdx.x;
  const int tx = tid & 7;
  const int ty = tid >> 3;
  const int half = tx >> 2;
  const int px = tx & 3;
  const int bid = blockIdx.x;
  const int nm = bid >> 8;    // 256 consecutive blocks share the w row
  const int tile = bid & 255;
  const int hw0 = tile * 16;
  const int n = nm >> 2;
  const int m = nm & 3;

  float* q_out = out;
  float* code_out = out + CODE_OFF;
  float* logit_out = out + LOGIT_OFF;

  // ---- stage x via global_load_lds (width 16); layout [c][half*16 + pos] ----
  {
    const float* xA = x + (size_t)(n * 256 + m * 64) * 4096 + hw0;
    const float* xB = xA + (size_t)4 * 256 * 4096;
#pragma unroll
    for (int it = 0; it < 2; ++it) {
      int idx = it * 256 + tid;        // float4 slot, 0..511
      int c = idx >> 3;                // 8 slots per channel (2 halves x 16 pos)
      int hs = (idx >> 2) & 1;
      int ck = idx & 3;
      const float* src = (hs ? xB : xA) + (size_t)c * 4096 + ck * 4;
      // wave-uniform LDS base; HW scatters lane*16
      float* dst = x_lds + ((it * 256 + (tid & ~63)) << 2);
      __builtin_amdgcn_global_load_lds((g_void*)src, (l_void*)dst, 16, 0, 0);
    }
  }

  const float* wrow = w + (size_t)m * 256 * 64;  // w[m][k][c], c contiguous
  float4 wr0;
  {  // chunk 0 of w (4 channels) into regs, then transposed to LDS buf0
    const float* wk = wrow + tid * 64;
    wr0 = *(const float4*)(wk + 0);
    w_lds[0 * 256 + tid] = wr0.x; w_lds[1 * 256 + tid] = wr0.y;
    w_lds[2 * 256 + tid] = wr0.z; w_lds[3 * 256 + tid] = wr0.w;
  }
  __syncthreads();  // drains x's lds-loads (vmcnt) + w writes

  // accumulators: acc{p}[jd]; gumbels gmb{p}[jd] (2 draws/chunk in-loop)
  float acc0[8], acc1[8], acc2[8], acc3[8];
  float gmb0[8], gmb1[8], gmb2[8], gmb3[8];
#pragma unroll
  for (int i = 0; i < 8; ++i) acc0[i] = acc1[i] = acc2[i] = acc3[i] = 0.0f;

  // flat draw index = ((nm + 16*half)*4096 + hw)*256 + k, hw = hw0 + 4*px + p
  const uint32_t base0 = ((uint32_t)((nm + 16 * half) * 4096 + hw0 + 4 * px)) << 8;

#pragma unroll
  for (int chunk = 0; chunk < 16; ++chunk) {
    if (chunk < 15) {  // prefetch next w chunk into regs (retires under compute)
      const float* wk = wrow + tid * 64 + (chunk + 1) * 4;
      wr0 = *(const float4*)wk;
    }
    {  // 2 threefry+gumbel draws per chunk (same flat indices as before)
#pragma unroll
      for (int i = 0; i < 2; ++i) {
        const int d = chunk * 2 + i;          // 0..31, compile-time after unroll
        const int p = d & 3, jj = d >> 2;     // covers all (p, jd) once
        const uint32_t k = (uint32_t)((jj >> 2) * 128 + ty * 4 + (jj & 3));
        const float g = bits_to_gumbel(tf32_part(base0 + (uint32_t)p * 256u + k));
        if (p == 0) gmb0[jj] = g;
        else if (p == 1) gmb1[jj] = g;
        else if (p == 2) gmb2[jj] = g;
        else gmb3[jj] = g;
      }
    }
    const int rb = (chunk & 1) << 10;  // read buffer base (1024 floats)
#pragma unroll
    for (int cc = 0; cc < 4; ++cc) {
      int c = chunk * 4 + cc;          // c ascending 0..63: chain order unchanged
      float4 xv = *(const float4*)&x_lds[c * 32 + half * 16 + px * 4];
      float wv[8];
      *(float4*)&wv[0] = *(const float4*)&w_lds[rb + cc * 256 +   0 + ty * 4];
      *(float4*)&wv[4] = *(const float4*)&w_lds[rb + cc * 256 + 128 + ty * 4];
#pragma unroll
      for (int jd = 0; jd < 8; ++jd) {
        float wkv = wv[jd];
        acc0[jd] += xv.x * wkv;
        acc1[jd] += xv.y * wkv;
        acc2[jd] += xv.z * wkv;
        acc3[jd] += xv.w * wkv;
      }
    }
    if (chunk < 15) {
      // write next chunk into the other buffer; its previous readers finished
      // before the barrier that ended chunk-1. One barrier per chunk total.
      const int wb = ((chunk + 1) & 1) << 10;
      w_lds[wb + 0 * 256 + tid] = wr0.x; w_lds[wb + 1 * 256 + tid] = wr0.y;
      w_lds[wb + 2 * 256 + tid] = wr0.z; w_lds[wb + 3 * 256 + tid] = wr0.w;
      __syncthreads();
    }
  }

  // ---- epilogue: float4 logit stores + argmax (gumbels already in regs) ----
  float best0 = -3.4e38f, best1 = -3.4e38f, best2 = -3.4e38f, best3 = -3.4e38f;
  int i0 = 0, i1 = 0, i2 = 0, i3 = 0;
  const size_t row_off = (size_t)hw0 + 4 * px;
#pragma unroll
  for (int jd = 0; jd < 8; ++jd) {
    int k = (jd >> 2) * 128 + ty * 4 + (jd & 3);
    size_t off = (size_t)((nm + 16 * half) * 256 + k) * 4096 + row_off;
    *(float4*)(logit_out + off) = make_float4(acc0[jd], acc1[jd], acc2[jd], acc3[jd]);
    float v0 = gmb0[jd] + acc0[jd];
    float v1 = gmb1[jd] + acc1[jd];
    float v2 = gmb2[jd] + acc2[jd];
    float v3 = gmb3[jd] + acc3[jd];
    // jd ascending => k ascending per thread; '>' keeps smallest k on ties
    if (v0 > best0) { best0 = v0; i0 = k; }
    if (v1 > best1) { best1 = v1; i1 = k; }
    if (v2 > best2) { best2 = v2; i2 = k; }
    if (v3 > best3) { best3 = v3; i3 = k; }
  }

  // ---- cross-thread argmax reduction over the 32 k-owners (ty) ----
  // red_val in x_lds, red_idx in w_lds: [32 slots][33] each (pad 33).
  __syncthreads();  // all compute reads of x_lds/w_lds done; reuse them
  float* red_val = x_lds;
  int* red_idx = (int*)w_lds;
  {
    int slot = half * 16 + px * 4;      // slot = half*16 + pos_local
    red_val[(slot + 0) * 33 + ty] = best0;  red_idx[(slot + 0) * 33 + ty] = i0;
    red_val[(slot + 1) * 33 + ty] = best1;  red_idx[(slot + 1) * 33 + ty] = i1;
    red_val[(slot + 2) * 33 + ty] = best2;  red_idx[(slot + 2) * 33 + ty] = i2;
    red_val[(slot + 3) * 33 + ty] = best3;  red_idx[(slot + 3) * 33 + ty] = i3;
  }
  __syncthreads();
  int* idx_final = (int*)(x_lds + 1088);  // 32 ints; past red_val's 1056 floats
  if (tid < 32) {
    float bv = -3.4e38f; int bi = 0x7fffffff;
#pragma unroll
    for (int t2 = 0; t2 < 32; ++t2) {
      float v = red_val[tid * 33 + t2];
      int ix = red_idx[tid * 33 + t2];
      if (v > bv || (v == bv && ix < bi)) { bv = v; bi = ix; }  // tie -> smallest k
    }
    idx_final[tid] = bi;
    int h = tid >> 4;
    int pos = tid & 15;
    code_out[(size_t)(nm + 16 * h) * 4096 + hw0 + pos] = (float)bi;
  }
  __syncthreads();

  // ---- one-hot q_out (race-free: every k written by its owner thread) ----
  const int f0 = idx_final[half * 16 + px * 4 + 0];
  const int f1 = idx_final[half * 16 + px * 4 + 1];
  const int f2 = idx_final[half * 16 + px * 4 + 2];
  const int f3 = idx_final[half * 16 + px * 4 + 3];
#pragma unroll
  for (int jd = 0; jd < 8; ++jd) {
    int k = (jd >> 2) * 128 + ty * 4 + (jd & 3);
    size_t off = (size_t)((nm + 16 * half) * 256 + k) * 4096 + row_off;
    *(float4*)(q_out + off) = make_float4(k == f0 ? 1.0f : 0.0f, k == f1 ? 1.0f : 0.0f,
                                          k == f2 ? 1.0f : 0.0f, k == f3 ? 1.0f : 0.0f);
  }
}

extern "C" void kernel_launch(void* const* d_in, const int* in_sizes, int n_in,
                              void* d_out, int out_size, void* d_ws, size_t ws_size,
                              hipStream_t stream) {
  const float* x = (const float*)d_in[0];  // [8][256][64][64] fp32
  const float* w = (const float*)d_in[1];  // [4][256][64] fp32
  float* out = (float*)d_out;
  mcq_kernel<<<dim3(4096), dim3(256), 0, stream>>>(x, w, out);
}

// Round 9
// 399.615 us; speedup vs baseline: 1.0156x; 1.0156x over previous
//
#include <hip/hip_runtime.h>
#include <stdint.h>

// Output layout (float32 elements within d_out):
//   q_out : [8][1024][64][64]  at offset 0          (33,554,432)
//   code  : [8][4][64][64]     at offset 33,554,432 (131,072)  -- stored as float
//   logit : [8][1024][64][64]  at offset 33,685,504 (33,554,432)
#define CODE_OFF  33554432u
#define LOGIT_OFF 33685504u

typedef __attribute__((address_space(1))) const void g_void;
typedef __attribute__((address_space(3))) void l_void;

__device__ __forceinline__ uint32_t rotl32(uint32_t x, int r) {
  return (x << r) | (x >> (32 - r));
}

// Partitionable threefry (JAX >= 0.4.36 default): counter words (0, flat_idx),
// key (0,42), 20 rounds, draw = o0 ^ o1. Verified bit-exact in round 2.
__device__ __forceinline__ uint32_t tf32_part(uint32_t i) {
  const uint32_t ks1 = 42u;
  const uint32_t ks2 = 0x1BD11BDAu ^ 42u;  // ks0 = 0
  uint32_t x0 = 0u;
  uint32_t x1 = i + ks1;
#define R4(a,b,c,d) \
  x0 += x1; x1 = rotl32(x1,(a)); x1 ^= x0; \
  x0 += x1; x1 = rotl32(x1,(b)); x1 ^= x0; \
  x0 += x1; x1 = rotl32(x1,(c)); x1 ^= x0; \
  x0 += x1; x1 = rotl32(x1,(d)); x1 ^= x0;
  R4(13,15,26,6)   x0 += ks1; x1 += ks2 + 1u;
  R4(17,29,16,24)  x0 += ks2; x1 += 2u;
  R4(13,15,26,6)               x1 += ks1 + 3u;
  R4(17,29,16,24)  x0 += ks1; x1 += ks2 + 4u;
  R4(13,15,26,6)   x0 += ks2; x1 += 5u;
#undef R4
  return x0 ^ x1;
}

__device__ __forceinline__ float bits_to_gumbel(uint32_t bits) {
  uint32_t fb = (bits >> 9) | 0x3f800000u;
  float f = __uint_as_float(fb) - 1.0f;
  float u = (f > 0.0f) ? f : 1.17549435e-38f;
  return -logf(-logf(u));
}

// Grid 4096, block 256 (4 waves). tx = tid&7: half = tx>>2 (n vs n+4),
// px = tx&3 -> 4 consecutive hw positions hw0 + 4*px + p (16-pos tile).
// ty = tid>>3 in [0,32): 8 k's per thread, k = g*128 + ty*4 + d.
// Same work geometry as the 382.7-best kernel. NEW: w staging is WAVE-PRIVATE.
// Wave w only reads k in [w*32,w*32+32) u [128+w*32,..+32) -> each wave stages
// its own 64 k-columns into its own LDS quarter. Same instruction count as the
// cooperative staging (8 gloads + 8 ds_writes per lane per chunk), but the DS
// pipe's per-wave in-order execution replaces __syncthreads: K-loop has ZERO
// barriers (was 7). Waves free-run; epilogue threefry of early waves overlaps
// K-loop of late waves. w_lds: [buf(2)][wave(4)][cc(8)][kl(64)] = 16 KB.
__global__ __launch_bounds__(256, 4)
void mcq_kernel(const float* __restrict__ x, const float* __restrict__ w,
                float* __restrict__ out) {
  __shared__ __align__(16) float x_lds[2048];  // [c(64)][half*16 + pos(16)]
  __shared__ __align__(16) float w_lds[4096];  // 2 x [wave(4)][cc(8)][kl(64)]

  const int tid = threadIdx.x;
  const int tx = tid & 7;
  const int ty = tid >> 3;
  const int half = tx >> 2;
  const int px = tx & 3;
  const int wave = tid >> 6;
  const int lane = tid & 63;
  const int tyl = (tid >> 3) & 7;      // ty within wave, 0..7
  const int bid = blockIdx.x;
  const int nm = bid >> 8;    // 256 consecutive blocks share the w row
  const int tile = bid & 255;
  const int hw0 = tile * 16;
  const int n = nm >> 2;
  const int m = nm & 3;

  float* q_out = out;
  float* code_out = out + CODE_OFF;
  float* logit_out = out + LOGIT_OFF;

  // ---- stage x via global_load_lds (width 16); layout [c][half*16 + pos] ----
  {
    const float* xA = x + (size_t)(n * 256 + m * 64) * 4096 + hw0;
    const float* xB = xA + (size_t)4 * 256 * 4096;
#pragma unroll
    for (int it = 0; it < 2; ++it) {
      int idx = it * 256 + tid;        // float4 slot, 0..511
      int c = idx >> 3;                // 8 slots per channel (2 halves x 16 pos)
      int hs = (idx >> 2) & 1;
      int ck = idx & 3;
      const float* src = (hs ? xB : xA) + (size_t)c * 4096 + ck * 4;
      // wave-uniform LDS base; HW scatters lane*16
      float* dst = x_lds + ((it * 256 + (tid & ~63)) << 2);
      __builtin_amdgcn_global_load_lds((g_void*)src, (l_void*)dst, 16, 0, 0);
    }
  }

  const float* wrow = w + (size_t)m * 256 * 64;  // w[m][k][c], c contiguous
  // This lane stages global k row: kstage = g*128 + wave*32 + (lane&31),
  // landing at wave-local column kl = lane ( = (lane>>5)*32 + (lane&31) ).
  const int kstage = ((lane >> 5) << 7) + (wave << 5) + (lane & 31);
  const float* wkbase = wrow + (size_t)kstage * 64;
  const int wslot = wave * 512 + lane;   // + j*64 per channel j
  float4 wr0, wr1;
  {  // chunk 0 of w (8 channels) into regs, then to this wave's LDS quarter
    wr0 = *(const float4*)(wkbase + 0);
    wr1 = *(const float4*)(wkbase + 4);
    w_lds[wslot + 0 * 64] = wr0.x; w_lds[wslot + 1 * 64] = wr0.y;
    w_lds[wslot + 2 * 64] = wr0.z; w_lds[wslot + 3 * 64] = wr0.w;
    w_lds[wslot + 4 * 64] = wr1.x; w_lds[wslot + 5 * 64] = wr1.y;
    w_lds[wslot + 6 * 64] = wr1.z; w_lds[wslot + 7 * 64] = wr1.w;
  }
  __syncthreads();  // drains x's lds-loads (vmcnt); the ONLY pre-epilogue barrier

  // accumulators: acc{p}[jd]; gumbels gmb{p}[jd] (computed in-loop, jd=chunk)
  float acc0[8], acc1[8], acc2[8], acc3[8];
  float gmb0[8], gmb1[8], gmb2[8], gmb3[8];
#pragma unroll
  for (int i = 0; i < 8; ++i) acc0[i] = acc1[i] = acc2[i] = acc3[i] = 0.0f;

  // flat draw index = ((nm + 16*half)*4096 + hw)*256 + k, hw = hw0 + 4*px + p
  const uint32_t base0 = ((uint32_t)((nm + 16 * half) * 4096 + hw0 + 4 * px)) << 8;

#pragma unroll
  for (int chunk = 0; chunk < 8; ++chunk) {
    if (chunk < 7) {  // prefetch next w chunk into regs (retires under compute)
      wr0 = *(const float4*)(wkbase + (chunk + 1) * 8);
      wr1 = *(const float4*)(wkbase + (chunk + 1) * 8 + 4);
    }
    {  // threefry + gumbel for jd = chunk (independent ALU: fills stalls)
      const uint32_t k = (uint32_t)((chunk >> 2) * 128 + ty * 4 + (chunk & 3));
      uint32_t b0 = tf32_part(base0 + 0u * 256u + k);
      uint32_t b1 = tf32_part(base0 + 1u * 256u + k);
      uint32_t b2 = tf32_part(base0 + 2u * 256u + k);
      uint32_t b3 = tf32_part(base0 + 3u * 256u + k);
      gmb0[chunk] = bits_to_gumbel(b0);
      gmb1[chunk] = bits_to_gumbel(b1);
      gmb2[chunk] = bits_to_gumbel(b2);
      gmb3[chunk] = bits_to_gumbel(b3);
    }
    const int rb = (chunk & 1) << 11;  // read buffer base
#pragma unroll
    for (int cc = 0; cc < 8; ++cc) {
      int c = chunk * 8 + cc;          // c ascending: chain order unchanged
      float4 xv = *(const float4*)&x_lds[c * 32 + half * 16 + px * 4];
      float wv[8];
      // wave-private reads: kl = tyl*4 (g=0) and 32 + tyl*4 (g=1)
      *(float4*)&wv[0] = *(const float4*)&w_lds[rb + wave * 512 + cc * 64 + tyl * 4];
      *(float4*)&wv[4] = *(const float4*)&w_lds[rb + wave * 512 + cc * 64 + 32 + tyl * 4];
#pragma unroll
      for (int jd = 0; jd < 8; ++jd) {
        float wkv = wv[jd];
        acc0[jd] += xv.x * wkv;
        acc1[jd] += xv.y * wkv;
        acc2[jd] += xv.z * wkv;
        acc3[jd] += xv.w * wkv;
      }
    }
    if (chunk < 7) {
      // write next chunk into the other buffer. Wave-private region + per-wave
      // in-order DS pipe -> NO barrier needed.
      const int wb = ((chunk + 1) & 1) << 11;
      w_lds[wb + wslot + 0 * 64] = wr0.x; w_lds[wb + wslot + 1 * 64] = wr0.y;
      w_lds[wb + wslot + 2 * 64] = wr0.z; w_lds[wb + wslot + 3 * 64] = wr0.w;
      w_lds[wb + wslot + 4 * 64] = wr1.x; w_lds[wb + wslot + 5 * 64] = wr1.y;
      w_lds[wb + wslot + 6 * 64] = wr1.z; w_lds[wb + wslot + 7 * 64] = wr1.w;
    }
  }

  // ---- epilogue: float4 logit stores + argmax (gumbels already in regs) ----
  float best0 = -3.4e38f, best1 = -3.4e38f, best2 = -3.4e38f, best3 = -3.4e38f;
  int i0 = 0, i1 = 0, i2 = 0, i3 = 0;
  const size_t row_off = (size_t)hw0 + 4 * px;
#pragma unroll
  for (int jd = 0; jd < 8; ++jd) {
    int k = (jd >> 2) * 128 + ty * 4 + (jd & 3);
    size_t off = (size_t)((nm + 16 * half) * 256 + k) * 4096 + row_off;
    *(float4*)(logit_out + off) = make_float4(acc0[jd], acc1[jd], acc2[jd], acc3[jd]);
    float v0 = gmb0[jd] + acc0[jd];
    float v1 = gmb1[jd] + acc1[jd];
    float v2 = gmb2[jd] + acc2[jd];
    float v3 = gmb3[jd] + acc3[jd];
    // jd ascending => k ascending per thread; '>' keeps smallest k on ties
    if (v0 > best0) { best0 = v0; i0 = k; }
    if (v1 > best1) { best1 = v1; i1 = k; }
    if (v2 > best2) { best2 = v2; i2 = k; }
    if (v3 > best3) { best3 = v3; i3 = k; }
  }

  // ---- cross-thread argmax reduction over the 32 k-owners (ty) ----
  // red_val in x_lds, red_idx in w_lds: [32 slots][33] each (pad 33).
  __syncthreads();  // all waves done with x_lds/w_lds; reuse them
  float* red_val = x_lds;
  int* red_idx = (int*)w_lds;
  {
    int slot = half * 16 + px * 4;      // slot = half*16 + pos_local
    red_val[(slot + 0) * 33 + ty] = best0;  red_idx[(slot + 0) * 33 + ty] = i0;
    red_val[(slot + 1) * 33 + ty] = best1;  red_idx[(slot + 1) * 33 + ty] = i1;
    red_val[(slot + 2) * 33 + ty] = best2;  red_idx[(slot + 2) * 33 + ty] = i2;
    red_val[(slot + 3) * 33 + ty] = best3;  red_idx[(slot + 3) * 33 + ty] = i3;
  }
  __syncthreads();
  int* idx_final = (int*)(x_lds + 1088);  // 32 ints; past red_val's 1056 floats
  if (tid < 32) {
    float bv = -3.4e38f; int bi = 0x7fffffff;
#pragma unroll
    for (int t2 = 0; t2 < 32; ++t2) {
      float v = red_val[tid * 33 + t2];
      int ix = red_idx[tid * 33 + t2];
      if (v > bv || (v == bv && ix < bi)) { bv = v; bi = ix; }  // tie -> smallest k
    }
    idx_final[tid] = bi;
    int h = tid >> 4;
    int pos = tid & 15;
    code_out[(size_t)(nm + 16 * h) * 4096 + hw0 + pos] = (float)bi;
  }
  __syncthreads();

  // ---- one-hot q_out (race-free: every k written by its owner thread) ----
  const int f0 = idx_final[half * 16 + px * 4 + 0];
  const int f1 = idx_final[half * 16 + px * 4 + 1];
  const int f2 = idx_final[half * 16 + px * 4 + 2];
  const int f3 = idx_final[half * 16 + px * 4 + 3];
#pragma unroll
  for (int jd = 0; jd < 8; ++jd) {
    int k = (jd >> 2) * 128 + ty * 4 + (jd & 3);
    size_t off = (size_t)((nm + 16 * half) * 256 + k) * 4096 + row_off;
    *(float4*)(q_out + off) = make_float4(k == f0 ? 1.0f : 0.0f, k == f1 ? 1.0f : 0.0f,
                                          k == f2 ? 1.0f : 0.0f, k == f3 ? 1.0f : 0.0f);
  }
}

extern "C" void kernel_launch(void* const* d_in, const int* in_sizes, int n_in,
                              void* d_out, int out_size, void* d_ws, size_t ws_size,
                              hipStream_t stream) {
  const float* x = (const float*)d_in[0];  // [8][256][64][64] fp32
  const float* w = (const float*)d_in[1];  // [4][256][64] fp32
  float* out = (float*)d_out;
  mcq_kernel<<<dim3(4096), dim3(256), 0, stream>>>(x, w, out);
}

// Round 10
// 386.065 us; speedup vs baseline: 1.0513x; 1.0351x over previous
//
#include <hip/hip_runtime.h>
#include <stdint.h>

// FINAL: revert to the session-best kernel (benched harness 382.7 µs,
// dispatch ~170 µs). Structure: 16-pos tile, 32 acc/thread, w double-buffered
// in LDS (7 in-loop barriers), in-loop threefry. All structural variants
// (more residency R1/R4/R8, zero barriers R6/R9, pk_fma R7, bigger tiles
// R0/R5) measured worse or spilled. Remaining levers (fast-log, bf16x3 MFMA)
// are correctness-gated by discrete argmax outputs.
//
// Output layout (float32 elements within d_out):
//   q_out : [8][1024][64][64]  at offset 0          (33,554,432)
//   code  : [8][4][64][64]     at offset 33,554,432 (131,072)  -- stored as float
//   logit : [8][1024][64][64]  at offset 33,685,504 (33,554,432)
#define CODE_OFF  33554432u
#define LOGIT_OFF 33685504u

typedef __attribute__((address_space(1))) const void g_void;
typedef __attribute__((address_space(3))) void l_void;

__device__ __forceinline__ uint32_t rotl32(uint32_t x, int r) {
  return (x << r) | (x >> (32 - r));
}

// Partitionable threefry (JAX >= 0.4.36 default): counter words (0, flat_idx),
// key (0,42), 20 rounds, draw = o0 ^ o1. Verified bit-exact in round 2.
__device__ __forceinline__ uint32_t tf32_part(uint32_t i) {
  const uint32_t ks1 = 42u;
  const uint32_t ks2 = 0x1BD11BDAu ^ 42u;  // ks0 = 0
  uint32_t x0 = 0u;
  uint32_t x1 = i + ks1;
#define R4(a,b,c,d) \
  x0 += x1; x1 = rotl32(x1,(a)); x1 ^= x0; \
  x0 += x1; x1 = rotl32(x1,(b)); x1 ^= x0; \
  x0 += x1; x1 = rotl32(x1,(c)); x1 ^= x0; \
  x0 += x1; x1 = rotl32(x1,(d)); x1 ^= x0;
  R4(13,15,26,6)   x0 += ks1; x1 += ks2 + 1u;
  R4(17,29,16,24)  x0 += ks2; x1 += 2u;
  R4(13,15,26,6)               x1 += ks1 + 3u;
  R4(17,29,16,24)  x0 += ks1; x1 += ks2 + 4u;
  R4(13,15,26,6)   x0 += ks2; x1 += 5u;
#undef R4
  return x0 ^ x1;
}

__device__ __forceinline__ float bits_to_gumbel(uint32_t bits) {
  uint32_t fb = (bits >> 9) | 0x3f800000u;
  float f = __uint_as_float(fb) - 1.0f;
  float u = (f > 0.0f) ? f : 1.17549435e-38f;
  return -logf(-logf(u));
}

// Grid 4096, block 256 (4 waves). tx = tid&7: half = tx>>2 (n vs n+4),
// px = tx&3 -> 4 consecutive hw positions hw0 + 4*px + p (16-pos tile).
// ty = tid>>3 in [0,32): 8 k's per thread, k = (jd>>2)*128 + ty*4 + (jd&3).
// K-loop: 8 chunks of 8 channels; w double-buffered (1 barrier/chunk);
// 2 threefry+gumbel draws per chunk (fills stalls).
__global__ __launch_bounds__(256, 4)
void mcq_kernel(const float* __restrict__ x, const float* __restrict__ w,
                float* __restrict__ out) {
  __shared__ __align__(16) float x_lds[2048];  // [c(64)][half*16 + pos(16)]
  __shared__ __align__(16) float w_lds[4096];  // 2 x [cc(8)][k(256)] buffers

  const int tid = threadIdx.x;
  const int tx = tid & 7;
  const int ty = tid >> 3;
  const int half = tx >> 2;
  const int px = tx & 3;
  const int bid = blockIdx.x;
  const int nm = bid >> 8;    // 256 consecutive blocks share the w row
  const int tile = bid & 255;
  const int hw0 = tile * 16;
  const int n = nm >> 2;
  const int m = nm & 3;

  float* q_out = out;
  float* code_out = out + CODE_OFF;
  float* logit_out = out + LOGIT_OFF;

  // ---- stage x via global_load_lds (width 16); layout [c][half*16 + pos] ----
  {
    const float* xA = x + (size_t)(n * 256 + m * 64) * 4096 + hw0;
    const float* xB = xA + (size_t)4 * 256 * 4096;
#pragma unroll
    for (int it = 0; it < 2; ++it) {
      int idx = it * 256 + tid;        // float4 slot, 0..511
      int c = idx >> 3;                // 8 slots per channel (2 halves x 16 pos)
      int hs = (idx >> 2) & 1;
      int ck = idx & 3;
      const float* src = (hs ? xB : xA) + (size_t)c * 4096 + ck * 4;
      // wave-uniform LDS base; HW scatters lane*16
      float* dst = x_lds + ((it * 256 + (tid & ~63)) << 2);
      __builtin_amdgcn_global_load_lds((g_void*)src, (l_void*)dst, 16, 0, 0);
    }
  }

  const float* wrow = w + (size_t)m * 256 * 64;  // w[m][k][c], c contiguous
  float4 wr0, wr1;
  {  // chunk 0 of w (8 channels) into regs, then transposed to LDS buf0
    const float* wk = wrow + tid * 64;
    wr0 = *(const float4*)(wk + 0);
    wr1 = *(const float4*)(wk + 4);
    w_lds[0 * 256 + tid] = wr0.x; w_lds[1 * 256 + tid] = wr0.y;
    w_lds[2 * 256 + tid] = wr0.z; w_lds[3 * 256 + tid] = wr0.w;
    w_lds[4 * 256 + tid] = wr1.x; w_lds[5 * 256 + tid] = wr1.y;
    w_lds[6 * 256 + tid] = wr1.z; w_lds[7 * 256 + tid] = wr1.w;
  }
  __syncthreads();  // drains x's lds-loads (vmcnt) + w writes

  // accumulators: acc{p}[jd]; gumbels gmb{p}[jd] (computed in-loop, jd=chunk)
  float acc0[8], acc1[8], acc2[8], acc3[8];
  float gmb0[8], gmb1[8], gmb2[8], gmb3[8];
#pragma unroll
  for (int i = 0; i < 8; ++i) acc0[i] = acc1[i] = acc2[i] = acc3[i] = 0.0f;

  // flat draw index = ((nm + 16*half)*4096 + hw) * 256 + k, hw = hw0 + 4*px + p
  const uint32_t base0 = ((uint32_t)((nm + 16 * half) * 4096 + hw0 + 4 * px)) << 8;

#pragma unroll
  for (int chunk = 0; chunk < 8; ++chunk) {
    if (chunk < 7) {  // prefetch next w chunk into regs (retires under compute)
      const float* wk = wrow + tid * 64 + (chunk + 1) * 8;
      wr0 = *(const float4*)(wk + 0);
      wr1 = *(const float4*)(wk + 4);
    }
    {  // threefry + gumbel for jd = chunk (independent ALU: fills stalls)
      const uint32_t k = (uint32_t)((chunk >> 2) * 128 + ty * 4 + (chunk & 3));
      uint32_t b0 = tf32_part(base0 + 0u * 256u + k);
      uint32_t b1 = tf32_part(base0 + 1u * 256u + k);
      uint32_t b2 = tf32_part(base0 + 2u * 256u + k);
      uint32_t b3 = tf32_part(base0 + 3u * 256u + k);
      gmb0[chunk] = bits_to_gumbel(b0);
      gmb1[chunk] = bits_to_gumbel(b1);
      gmb2[chunk] = bits_to_gumbel(b2);
      gmb3[chunk] = bits_to_gumbel(b3);
    }
    const int rb = (chunk & 1) << 11;  // read buffer base
#pragma unroll
    for (int cc = 0; cc < 8; ++cc) {
      int c = chunk * 8 + cc;
      float4 xv = *(const float4*)&x_lds[c * 32 + half * 16 + px * 4];
      float wv[8];
      *(float4*)&wv[0] = *(const float4*)&w_lds[rb + cc * 256 +   0 + ty * 4];
      *(float4*)&wv[4] = *(const float4*)&w_lds[rb + cc * 256 + 128 + ty * 4];
#pragma unroll
      for (int jd = 0; jd < 8; ++jd) {
        float wkv = wv[jd];
        acc0[jd] += xv.x * wkv;
        acc1[jd] += xv.y * wkv;
        acc2[jd] += xv.z * wkv;
        acc3[jd] += xv.w * wkv;
      }
    }
    if (chunk < 7) {
      // write next chunk into the other buffer; its previous readers finished
      // before the barrier that ended chunk-1. One barrier per chunk total.
      const int wb = ((chunk + 1) & 1) << 11;
      w_lds[wb + 0 * 256 + tid] = wr0.x; w_lds[wb + 1 * 256 + tid] = wr0.y;
      w_lds[wb + 2 * 256 + tid] = wr0.z; w_lds[wb + 3 * 256 + tid] = wr0.w;
      w_lds[wb + 4 * 256 + tid] = wr1.x; w_lds[wb + 5 * 256 + tid] = wr1.y;
      w_lds[wb + 6 * 256 + tid] = wr1.z; w_lds[wb + 7 * 256 + tid] = wr1.w;
      __syncthreads();
    }
  }

  // ---- epilogue: float4 logit stores + argmax (gumbels already in regs) ----
  float best0 = -3.4e38f, best1 = -3.4e38f, best2 = -3.4e38f, best3 = -3.4e38f;
  int i0 = 0, i1 = 0, i2 = 0, i3 = 0;
  const size_t row_off = (size_t)hw0 + 4 * px;
#pragma unroll
  for (int jd = 0; jd < 8; ++jd) {
    int k = (jd >> 2) * 128 + ty * 4 + (jd & 3);
    size_t off = (size_t)((nm + 16 * half) * 256 + k) * 4096 + row_off;
    *(float4*)(logit_out + off) = make_float4(acc0[jd], acc1[jd], acc2[jd], acc3[jd]);
    float v0 = gmb0[jd] + acc0[jd];
    float v1 = gmb1[jd] + acc1[jd];
    float v2 = gmb2[jd] + acc2[jd];
    float v3 = gmb3[jd] + acc3[jd];
    // jd ascending => k ascending per thread; '>' keeps smallest k on ties
    if (v0 > best0) { best0 = v0; i0 = k; }
    if (v1 > best1) { best1 = v1; i1 = k; }
    if (v2 > best2) { best2 = v2; i2 = k; }
    if (v3 > best3) { best3 = v3; i3 = k; }
  }

  // ---- cross-thread argmax reduction over the 32 k-owners (ty) ----
  // red_val in x_lds, red_idx in w_lds: [32 slots][33] each (pad 33).
  __syncthreads();  // all compute reads of x_lds/w_lds done; reuse them
  float* red_val = x_lds;
  int* red_idx = (int*)w_lds;
  {
    int slot = half * 16 + px * 4;      // slot = half*16 + pos_local
    red_val[(slot + 0) * 33 + ty] = best0;  red_idx[(slot + 0) * 33 + ty] = i0;
    red_val[(slot + 1) * 33 + ty] = best1;  red_idx[(slot + 1) * 33 + ty] = i1;
    red_val[(slot + 2) * 33 + ty] = best2;  red_idx[(slot + 2) * 33 + ty] = i2;
    red_val[(slot + 3) * 33 + ty] = best3;  red_idx[(slot + 3) * 33 + ty] = i3;
  }
  __syncthreads();
  int* idx_final = (int*)(x_lds + 1088);  // 32 ints; past red_val's 1056 floats
  if (tid < 32) {
    float bv = -3.4e38f; int bi = 0x7fffffff;
#pragma unroll
    for (int t2 = 0; t2 < 32; ++t2) {
      float v = red_val[tid * 33 + t2];
      int ix = red_idx[tid * 33 + t2];
      if (v > bv || (v == bv && ix < bi)) { bv = v; bi = ix; }  // tie -> smallest k
    }
    idx_final[tid] = bi;
    int h = tid >> 4;
    int pos = tid & 15;
    code_out[(size_t)(nm + 16 * h) * 4096 + hw0 + pos] = (float)bi;
  }
  __syncthreads();

  // ---- one-hot q_out (race-free: every k written by its owner thread) ----
  const int f0 = idx_final[half * 16 + px * 4 + 0];
  const int f1 = idx_final[half * 16 + px * 4 + 1];
  const int f2 = idx_final[half * 16 + px * 4 + 2];
  const int f3 = idx_final[half * 16 + px * 4 + 3];
#pragma unroll
  for (int jd = 0; jd < 8; ++jd) {
    int k = (jd >> 2) * 128 + ty * 4 + (jd & 3);
    size_t off = (size_t)((nm + 16 * half) * 256 + k) * 4096 + row_off;
    *(float4*)(q_out + off) = make_float4(k == f0 ? 1.0f : 0.0f, k == f1 ? 1.0f : 0.0f,
                                          k == f2 ? 1.0f : 0.0f, k == f3 ? 1.0f : 0.0f);
  }
}

extern "C" void kernel_launch(void* const* d_in, const int* in_sizes, int n_in,
                              void* d_out, int out_size, void* d_ws, size_t ws_size,
                              hipStream_t stream) {
  const float* x = (const float*)d_in[0];  // [8][256][64][64] fp32
  const float* w = (const float*)d_in[1];  // [4][256][64] fp32
  float* out = (float*)d_out;
  mcq_kernel<<<dim3(4096), dim3(256), 0, stream>>>(x, w, out);
}